// Round 19
// baseline (583.138 us; speedup 1.0000x reference)
//
#include <hip/hip_runtime.h>
#include <hip/hip_bf16.h>

#define NN 100000
#define NE 1600000
// HID=256, HEADS=4, HEAD_DIM=64

typedef __attribute__((ext_vector_type(8))) short bf16x8;
typedef __attribute__((ext_vector_type(4))) float f32x4;
typedef __attribute__((ext_vector_type(2))) float f32x2;
typedef __attribute__((ext_vector_type(2))) unsigned int u32x2;
typedef __attribute__((ext_vector_type(4))) unsigned int u32x4;

// ---------- helpers ----------
__device__ __forceinline__ float bf2f(unsigned short u) {
    union { unsigned int i; float f; } c; c.i = ((unsigned int)u) << 16; return c.f;
}
__device__ __forceinline__ unsigned short f2bf(float f) {
    union { float f; unsigned int i; } c; c.f = f;
    unsigned int lsb = (c.i >> 16) & 1u;
    c.i += 0x7FFFu + lsb;   // round-to-nearest-even
    return (unsigned short)(c.i >> 16);
}
__device__ __forceinline__ u32x4 pack8bf(f32x4 a, f32x4 b) {
    u32x4 p;
    p.x = f2bf(a[0]) | ((unsigned int)f2bf(a[1]) << 16);
    p.y = f2bf(a[2]) | ((unsigned int)f2bf(a[3]) << 16);
    p.z = f2bf(b[0]) | ((unsigned int)f2bf(b[1]) << 16);
    p.w = f2bf(b[2]) | ((unsigned int)f2bf(b[3]) << 16);
    return p;
}
__device__ __forceinline__ unsigned int pack4fp8(f32x4 v) {
    unsigned int w = __builtin_amdgcn_cvt_pk_fp8_f32(v[0], v[1], 0, false);
    return __builtin_amdgcn_cvt_pk_fp8_f32(v[2], v[3], w, true);
}
__device__ __forceinline__ void gload_lds16(const void* g, void* l) {
    __builtin_amdgcn_global_load_lds(
        (const __attribute__((address_space(1))) void*)g,
        (__attribute__((address_space(3))) void*)l, 16, 0, 0);
}

// ---------- LayerNorm (LN1): 4 rows/block, 1 wave/row, bf16 out ----------
__global__ __launch_bounds__(256) void ln_k(
    const float* __restrict__ x, const float* __restrict__ g,
    const float* __restrict__ b, unsigned short* __restrict__ y, int nrows)
{
    int w = threadIdx.x >> 6, lane = threadIdx.x & 63;
    int row = blockIdx.x * 4 + w;
    if (row >= nrows) return;
    const float4 xv = *(const float4*)(x + (size_t)row * 256 + lane * 4);
    float s  = xv.x + xv.y + xv.z + xv.w;
    float sq = xv.x*xv.x + xv.y*xv.y + xv.z*xv.z + xv.w*xv.w;
    #pragma unroll
    for (int m = 1; m < 64; m <<= 1) {
        s  += __shfl_xor(s,  m);
        sq += __shfl_xor(sq, m);
    }
    float mu  = s * (1.0f / 256.0f);
    float var = sq * (1.0f / 256.0f) - mu * mu;
    float r = rsqrtf(var + 1e-5f);
    float4 gv = *(const float4*)(g + lane * 4);
    float4 bv = *(const float4*)(b + lane * 4);
    ushort4 o;
    o.x = f2bf((xv.x - mu) * r * gv.x + bv.x);
    o.y = f2bf((xv.y - mu) * r * gv.y + bv.y);
    o.z = f2bf((xv.z - mu) * r * gv.z + bv.z);
    o.w = f2bf((xv.w - mu) * r * gv.w + bv.w);
    *(ushort4*)(y + (size_t)row * 256 + lane * 4) = o;
}

// ---------- fused weight conversion: all transposes + bias concat in ONE kernel ----------
__global__ __launch_bounds__(256) void wcv_all_k(
    const float* __restrict__ Wq, const float* __restrict__ Wk, const float* __restrict__ Wv,
    const float* __restrict__ Wo, const float* __restrict__ W1, const float* __restrict__ W2,
    unsigned short* __restrict__ Wqkvt, unsigned short* __restrict__ Wot,
    unsigned short* __restrict__ W1t, unsigned short* __restrict__ W2t,
    const float* __restrict__ bq, const float* __restrict__ bk, const float* __restrict__ bv,
    float* __restrict__ bqkv)
{
    int id = blockIdx.x;
    int t = threadIdx.x;
    if (id == 512) {
        bqkv[t] = bq[t]; bqkv[256 + t] = bk[t]; bqkv[512 + t] = bv[t];
        return;
    }
    const float* W; unsigned short* Wt; int K, N, kx, ny;
    if (id < 192) {
        int grp = id >> 6, l = id & 63;
        W = (grp == 0) ? Wq : ((grp == 1) ? Wk : Wv);
        Wt = Wqkvt + grp * 256 * 256;
        K = 256; N = 256; kx = l & 7; ny = l >> 3;
    } else if (id < 256) {
        int l = id - 192; W = Wo; Wt = Wot; K = 256; N = 256; kx = l & 7; ny = l >> 3;
    } else if (id < 384) {
        int l = id - 256; W = W1; Wt = W1t; K = 256; N = 512; kx = l & 7; ny = l >> 3;
    } else {
        int l = id - 384; W = W2; Wt = W2t; K = 512; N = 256; kx = l & 15; ny = l >> 4;
    }
    __shared__ unsigned short tl[32][33];
    int bk2 = kx * 32, bn = ny * 32;
    int lx = t & 31, ly = t >> 5;
    #pragma unroll
    for (int r = 0; r < 32; r += 8)
        tl[ly + r][lx] = f2bf(W[(size_t)(bk2 + ly + r) * N + bn + lx]);
    __syncthreads();
    #pragma unroll
    for (int r = 0; r < 32; r += 8)
        Wt[(size_t)(bn + ly + r) * K + bk2 + lx] = tl[lx][ly + r];
}

// ---------- MFMA bf16 GEMM v5: 3-buffer 2-deep counted-vmcnt pipeline ----------
// 128x256 tile, BK=32, 512 threads = 8 waves (2Mx4N)
// NBX: 0 = 2D launch; >0 = 1D XCD-swizzled (bijective)
// OMODE: 2 QKV split (Q bf16 / KV fp8) | 3 Wo+LN2 fused (outv=h2 bf16, out2=hmid bf16, res=h f32)
template<int NBX, int OMODE, bool RELU, bool RES>
__global__ __launch_bounds__(512) void mgemm_k(
    const unsigned short* __restrict__ A, const unsigned short* __restrict__ Wt,
    const float* __restrict__ bias, void* __restrict__ outv, void* __restrict__ out2,
    const void* __restrict__ res, const float* __restrict__ g, const float* __restrict__ be,
    int M, int N, int K)
{
    __shared__ __align__(16) char lds[73728];
    const int t = threadIdx.x;
    const int lane = t & 63;
    const int wid = t >> 6;
    const int wm = wid >> 2, wn = wid & 3;

    int bmi, bni;
    if (NBX > 0) {
        const int nwg = gridDim.x;
        const int q = nwg >> 3, r = nwg & 7;
        const int xcd = blockIdx.x & 7, idx = blockIdx.x >> 3;
        const int wgid = (xcd < r) ? (xcd * (q + 1) + idx)
                                   : (r * (q + 1) + (xcd - r) * q + idx);
        bmi = wgid / NBX; bni = wgid - bmi * NBX;
    } else {
        bmi = blockIdx.y; bni = blockIdx.x;
    }
    const int bm = bmi * 128, bn = bni * 256;

    f32x4 acc[4][4] = {};

    const int ra_s = t >> 2;
    const int sa_s = (t & 3) ^ (ra_s & 3);
    const size_t arow = (size_t)min(bm + ra_s, M - 1) * K + sa_s * 8;
    const int rb0 = t >> 2;
    const int sb0 = (t & 3) ^ (rb0 & 3);
    const int rb1 = (512 + t) >> 2;
    const int sb1 = (t & 3) ^ (rb1 & 3);
    const size_t brow0 = (size_t)(bn + rb0) * K + sb0 * 8;
    const size_t brow1 = (size_t)(bn + rb1) * K + sb1 * 8;

    const int fr = lane & 15, fs = lane >> 4;
    const int rslot = fs ^ (fr & 3);

    const int KS = K >> 5;

#define STAGE(b, k0) { \
        unsigned short* Ab = (unsigned short*)(lds + (b) * 8192); \
        unsigned short* Bb = (unsigned short*)(lds + 24576 + (b) * 16384); \
        const int kk_ = (k0) << 5; \
        gload_lds16(A + arow + kk_, Ab + t * 8); \
        gload_lds16(Wt + brow0 + kk_, Bb + t * 8); \
        gload_lds16(Wt + brow1 + kk_, Bb + (512 + t) * 8); }

    STAGE(0, 0)
    STAGE(1, 1)
    int cur = 0;
    for (int ks = 0; ks < KS; ++ks) {
        if (ks + 1 < KS) asm volatile("s_waitcnt vmcnt(3)" ::: "memory");
        else             asm volatile("s_waitcnt vmcnt(0)" ::: "memory");
        __builtin_amdgcn_s_barrier();
        if (ks + 2 < KS) {
            int nb = cur + 2; if (nb >= 3) nb -= 3;
            STAGE(nb, ks + 2)
        }
        const unsigned short* As = (const unsigned short*)(lds + cur * 8192);
        const unsigned short* Bs = (const unsigned short*)(lds + 24576 + cur * 16384);
        bf16x8 af[4], bf[4];
        #pragma unroll
        for (int fm = 0; fm < 4; ++fm)
            af[fm] = *(const bf16x8*)&As[(wm * 64 + fm * 16 + fr) * 32 + rslot * 8];
        #pragma unroll
        for (int fn = 0; fn < 4; ++fn)
            bf[fn] = *(const bf16x8*)&Bs[(wn * 64 + fn * 16 + fr) * 32 + rslot * 8];
        #pragma unroll
        for (int fm = 0; fm < 4; ++fm)
            #pragma unroll
            for (int fn = 0; fn < 4; ++fn)
                acc[fm][fn] = __builtin_amdgcn_mfma_f32_16x16x32_bf16(
                    af[fm], bf[fn], acc[fm][fn], 0, 0, 0);
        if (++cur == 3) cur = 0;
    }
#undef STAGE
    __syncthreads();

    // epilogue: per-wave LDS bounce [16 rows][68 stride f32]
    float* wl = (float*)(lds + wid * 4352);
    float* stats = (float*)(lds + 34816);
    const int rr = lane >> 2;
    const int c4 = (lane & 3) * 16;
    const int qg = lane >> 4;

    #pragma unroll
    for (int fm = 0; fm < 4; ++fm) {
        #pragma unroll
        for (int fn = 0; fn < 4; ++fn)
            #pragma unroll
            for (int i = 0; i < 4; ++i)
                wl[(qg * 4 + i) * 68 + fn * 16 + fr] = acc[fm][fn][i];
        f32x4 v0 = *(const f32x4*)&wl[rr * 68 + c4 + 0];
        f32x4 v1 = *(const f32x4*)&wl[rr * 68 + c4 + 4];
        f32x4 v2 = *(const f32x4*)&wl[rr * 68 + c4 + 8];
        f32x4 v3 = *(const f32x4*)&wl[rr * 68 + c4 + 12];
        const int rowg = bm + wm * 64 + fm * 16 + rr;
        const int colg = bn + wn * 64 + c4;
        if (rowg < M) {
            v0 += *(const f32x4*)&bias[colg + 0];
            v1 += *(const f32x4*)&bias[colg + 4];
            v2 += *(const f32x4*)&bias[colg + 8];
            v3 += *(const f32x4*)&bias[colg + 12];
            if (RES) {
                const float* rp = (const float*)res + (size_t)rowg * N + colg;
                v0 += *(const f32x4*)(rp + 0);
                v1 += *(const f32x4*)(rp + 4);
                v2 += *(const f32x4*)(rp + 8);
                v3 += *(const f32x4*)(rp + 12);
            }
            if (RELU) {
                #pragma unroll
                for (int j = 0; j < 4; ++j) {
                    v0[j] = fmaxf(v0[j], 0.f); v1[j] = fmaxf(v1[j], 0.f);
                    v2[j] = fmaxf(v2[j], 0.f); v3[j] = fmaxf(v3[j], 0.f);
                }
            }
        } else {
            v0 = 0.f; v1 = 0.f; v2 = 0.f; v3 = 0.f;
        }

        if (OMODE == 3) {
            acc[fm][0] = v0; acc[fm][1] = v1; acc[fm][2] = v2; acc[fm][3] = v3;
        } else if (rowg < M) {
            // OMODE 2: QKV split
            if (colg < 256) {
                unsigned short* op = (unsigned short*)outv + (size_t)rowg * 256 + colg;
                *(u32x4*)(op + 0) = pack8bf(v0, v1);
                *(u32x4*)(op + 8) = pack8bf(v2, v3);
            } else {
                u32x4 p8;
                p8.x = pack4fp8(v0); p8.y = pack4fp8(v1);
                p8.z = pack4fp8(v2); p8.w = pack4fp8(v3);
                *(u32x4*)((unsigned char*)out2 + (size_t)rowg * 512 + (colg - 256)) = p8;
            }
        }
    }

    if (OMODE == 3) {
        #pragma unroll
        for (int fm = 0; fm < 4; ++fm) {
            float s = 0.f, q = 0.f;
            #pragma unroll
            for (int j = 0; j < 4; ++j)
                #pragma unroll
                for (int c = 0; c < 4; ++c) {
                    float x = acc[fm][j][c];
                    s += x; q += x * x;
                }
            s += __shfl_xor(s, 1); q += __shfl_xor(q, 1);
            s += __shfl_xor(s, 2); q += __shfl_xor(q, 2);
            if ((lane & 3) == 0) {
                int rowl = wm * 64 + fm * 16 + rr;
                stats[rowl * 8 + wn * 2 + 0] = s;
                stats[rowl * 8 + wn * 2 + 1] = q;
            }
        }
        __syncthreads();
        #pragma unroll
        for (int fm = 0; fm < 4; ++fm) {
            const int rowl = wm * 64 + fm * 16 + rr;
            const int rowg = bm + rowl;
            float s = stats[rowl * 8 + 0] + stats[rowl * 8 + 2] + stats[rowl * 8 + 4] + stats[rowl * 8 + 6];
            float q = stats[rowl * 8 + 1] + stats[rowl * 8 + 3] + stats[rowl * 8 + 5] + stats[rowl * 8 + 7];
            float mu = s * (1.0f / 256.0f);
            float var = q * (1.0f / 256.0f) - mu * mu;
            float rstd = rsqrtf(var + 1e-5f);
            const int colg = bn + wn * 64 + c4;
            if (rowg < M) {
                unsigned short* mp = (unsigned short*)out2 + (size_t)rowg * 256 + colg;
                *(u32x4*)(mp + 0) = pack8bf(acc[fm][0], acc[fm][1]);
                *(u32x4*)(mp + 8) = pack8bf(acc[fm][2], acc[fm][3]);
                f32x4 nv[4];
                #pragma unroll
                for (int j = 0; j < 4; ++j) {
                    f32x4 gv = *(const f32x4*)&g[colg + j * 4];
                    f32x4 bv = *(const f32x4*)&be[colg + j * 4];
                    #pragma unroll
                    for (int c = 0; c < 4; ++c)
                        nv[j][c] = (acc[fm][j][c] - mu) * rstd * gv[c] + bv[c];
                }
                unsigned short* op = (unsigned short*)outv + (size_t)rowg * 256 + colg;
                *(u32x4*)(op + 0) = pack8bf(nv[0], nv[1]);
                *(u32x4*)(op + 8) = pack8bf(nv[2], nv[3]);
            }
        }
    }
}

// ---------- fused FFN v3.1: 64-row tiles, 80KB LDS -> 2 workgroups/CU ----------
// 512 threads = 8 waves (2Mx4N), wave = 32 rows x 64 cols, acc 2x4
// LDS: A 32KB @0 (8 chunks x 4KB) | B 16KB @32768 (single) | FF 32KB @49152
// pack bounce @32768 spans B+FF-head (dead at that moment, WAR-protected by barrier)
__global__ __launch_bounds__(512, 4) void mffn_k(
    const unsigned short* __restrict__ A,     // h2 [M][256] bf16
    const unsigned short* __restrict__ W1t,   // [512][256] bf16
    const unsigned short* __restrict__ W2t,   // [256][512] bf16
    const float* __restrict__ b1, const float* __restrict__ b2,
    const unsigned short* __restrict__ hmid,  // [M][256] bf16 residual
    float* __restrict__ out, int M)
{
    __shared__ __align__(16) char lds[81920];
    char* Alds = lds;            // 32768
    char* Blds = lds + 32768;    // 16384
    char* Flds = lds + 49152;    // 32768

    const int t = threadIdx.x;
    const int lane = t & 63;
    const int wid = t >> 6;
    const int wm = wid >> 2, wn = wid & 3;
    const int bm = blockIdx.y * 64;
    const int fr = lane & 15, fs = lane >> 4;
    const int rslot = fs ^ (fr & 3);

    // ---- stage full A tile: 8 chunks x 4KB; half-block per chunk parity ----
    {
        const int tt = t & 255, tc = t >> 8;
        const int rowA = tt >> 2;
        const int slotA = (tt & 3) ^ (rowA & 3);
        const size_t abase = (size_t)min(bm + rowA, M - 1) * 256 + slotA * 8;
        #pragma unroll
        for (int kc0 = 0; kc0 < 8; kc0 += 2) {
            int kc = kc0 + tc;
            gload_lds16(A + abase + kc * 32, Alds + kc * 4096 + tt * 16);
        }
    }

    const int rb0 = t >> 2;
    const int sb0 = (t & 3) ^ (rb0 & 3);
    const int rb1 = (512 + t) >> 2;
    const int sb1 = (t & 3) ^ (rb1 & 3);

    f32x4 acc2[2][4] = {};
    const int rr = lane >> 2;
    const int qg = lane >> 4;
    const int c4 = (lane & 3) * 16;

    for (int nh = 0; nh < 2; ++nh) {
        // ---- FFN1 half: acc1 = A x W1t[nh*256 .. +256][:] ----
        f32x4 acc1[2][4] = {};
        {
            const unsigned short* B1 = W1t + (size_t)(nh * 256) * 256;
            for (int ks = 0; ks < 8; ++ks) {
                __syncthreads();    // prev step's B readers done (also drains A stage on first)
                gload_lds16(B1 + (size_t)rb0 * 256 + sb0 * 8 + ks * 32, Blds + t * 16);
                gload_lds16(B1 + (size_t)rb1 * 256 + sb1 * 8 + ks * 32, Blds + 8192 + t * 16);
                __syncthreads();    // B(ks) visible
                const unsigned short* As = (const unsigned short*)(Alds + ks * 4096);
                const unsigned short* Bs = (const unsigned short*)Blds;
                bf16x8 af[2], bf[4];
                #pragma unroll
                for (int fm = 0; fm < 2; ++fm)
                    af[fm] = *(const bf16x8*)&As[(wm * 32 + fm * 16 + fr) * 32 + rslot * 8];
                #pragma unroll
                for (int fn = 0; fn < 4; ++fn)
                    bf[fn] = *(const bf16x8*)&Bs[(wn * 64 + fn * 16 + fr) * 32 + rslot * 8];
                #pragma unroll
                for (int fm = 0; fm < 2; ++fm)
                    #pragma unroll
                    for (int fn = 0; fn < 4; ++fn)
                        acc1[fm][fn] = __builtin_amdgcn_mfma_f32_16x16x32_bf16(
                            af[fm], bf[fn], acc1[fm][fn], 0, 0, 0);
            }
        }
        __syncthreads();   // *** WAR fix: all waves' last Bs reads done before bounce
                           // scribbles over the B region (R18 NaN root cause) ***

        // ---- bounce acc1 -> row-major, +bias, relu, pack to regs (per-wave private) ----
        u32x4 pk[2][2];
        {
            float* wl = (float*)(lds + 32768 + wid * 4352);   // B + FF-head, dead here
            #pragma unroll
            for (int fm = 0; fm < 2; ++fm) {
                #pragma unroll
                for (int fn = 0; fn < 4; ++fn)
                    #pragma unroll
                    for (int i = 0; i < 4; ++i)
                        wl[(qg * 4 + i) * 68 + fn * 16 + fr] = acc1[fm][fn][i];
                f32x4 v0 = *(const f32x4*)&wl[rr * 68 + c4 + 0];
                f32x4 v1 = *(const f32x4*)&wl[rr * 68 + c4 + 4];
                f32x4 v2 = *(const f32x4*)&wl[rr * 68 + c4 + 8];
                f32x4 v3 = *(const f32x4*)&wl[rr * 68 + c4 + 12];
                const int colg = wn * 64 + c4;
                v0 += *(const f32x4*)&b1[nh * 256 + colg + 0];
                v1 += *(const f32x4*)&b1[nh * 256 + colg + 4];
                v2 += *(const f32x4*)&b1[nh * 256 + colg + 8];
                v3 += *(const f32x4*)&b1[nh * 256 + colg + 12];
                #pragma unroll
                for (int j = 0; j < 4; ++j) {
                    v0[j] = fmaxf(v0[j], 0.f); v1[j] = fmaxf(v1[j], 0.f);
                    v2[j] = fmaxf(v2[j], 0.f); v3[j] = fmaxf(v3[j], 0.f);
                }
                pk[fm][0] = pack8bf(v0, v1);
                pk[fm][1] = pack8bf(v2, v3);
            }
        }
        __syncthreads();   // all packs done; bounce region dead -> FF writable

        // ---- vectorized FF writes: swizzled A-fragment layout ----
        {
            const int cg = wn * 64 + c4;
            const int kc = cg >> 5;
            const int o1 = (cg >> 3) & 3;
            #pragma unroll
            for (int fm = 0; fm < 2; ++fm) {
                const int row = wm * 32 + fm * 16 + rr;
                char* base = Flds + kc * 4096 + row * 64;
                *(u32x4*)(base + ((o1 ^ (row & 3)) * 16))       = pk[fm][0];
                *(u32x4*)(base + (((o1 + 1) ^ (row & 3)) * 16)) = pk[fm][1];
            }
        }
        __syncthreads();   // FF visible to all waves

        // ---- FFN2 half: acc2 += FF x W2t[:, nh*256 .. +256] ----
        {
            const unsigned short* B2 = W2t + nh * 256;
            for (int ks = 0; ks < 8; ++ks) {
                __syncthreads();
                gload_lds16(B2 + (size_t)rb0 * 512 + sb0 * 8 + ks * 32, Blds + t * 16);
                gload_lds16(B2 + (size_t)rb1 * 512 + sb1 * 8 + ks * 32, Blds + 8192 + t * 16);
                __syncthreads();
                const unsigned short* Fs = (const unsigned short*)(Flds + ks * 4096);
                const unsigned short* Bs = (const unsigned short*)Blds;
                bf16x8 af[2], bf[4];
                #pragma unroll
                for (int fm = 0; fm < 2; ++fm)
                    af[fm] = *(const bf16x8*)&Fs[(wm * 32 + fm * 16 + fr) * 32 + rslot * 8];
                #pragma unroll
                for (int fn = 0; fn < 4; ++fn)
                    bf[fn] = *(const bf16x8*)&Bs[(wn * 64 + fn * 16 + fr) * 32 + rslot * 8];
                #pragma unroll
                for (int fm = 0; fm < 2; ++fm)
                    #pragma unroll
                    for (int fn = 0; fn < 4; ++fn)
                        acc2[fm][fn] = __builtin_amdgcn_mfma_f32_16x16x32_bf16(
                            af[fm], bf[fn], acc2[fm][fn], 0, 0, 0);
            }
        }
        __syncthreads();   // FFN2 LDS reads done before next nh's bounce/B-stage overwrite
    }

    // ---- epilogue: + b2 + hmid(bf16) -> out f32 (bounce in A region, now dead) ----
    float* wl = (float*)(Alds + wid * 4352);
    #pragma unroll
    for (int fm = 0; fm < 2; ++fm) {
        #pragma unroll
        for (int fn = 0; fn < 4; ++fn)
            #pragma unroll
            for (int i = 0; i < 4; ++i)
                wl[(qg * 4 + i) * 68 + fn * 16 + fr] = acc2[fm][fn][i];
        f32x4 v0 = *(const f32x4*)&wl[rr * 68 + c4 + 0];
        f32x4 v1 = *(const f32x4*)&wl[rr * 68 + c4 + 4];
        f32x4 v2 = *(const f32x4*)&wl[rr * 68 + c4 + 8];
        f32x4 v3 = *(const f32x4*)&wl[rr * 68 + c4 + 12];
        const int rowg = bm + wm * 32 + fm * 16 + rr;
        const int colg = wn * 64 + c4;
        if (rowg < M) {
            v0 += *(const f32x4*)&b2[colg + 0];
            v1 += *(const f32x4*)&b2[colg + 4];
            v2 += *(const f32x4*)&b2[colg + 8];
            v3 += *(const f32x4*)&b2[colg + 12];
            const unsigned short* rp = hmid + (size_t)rowg * 256 + colg;
            u32x4 ra4 = *(const u32x4*)rp;
            u32x4 rb4 = *(const u32x4*)(rp + 8);
            v0[0] += bf2f(ra4.x & 0xffff); v0[1] += bf2f(ra4.x >> 16);
            v0[2] += bf2f(ra4.y & 0xffff); v0[3] += bf2f(ra4.y >> 16);
            v1[0] += bf2f(ra4.z & 0xffff); v1[1] += bf2f(ra4.z >> 16);
            v1[2] += bf2f(ra4.w & 0xffff); v1[3] += bf2f(ra4.w >> 16);
            v2[0] += bf2f(rb4.x & 0xffff); v2[1] += bf2f(rb4.x >> 16);
            v2[2] += bf2f(rb4.y & 0xffff); v2[3] += bf2f(rb4.y >> 16);
            v3[0] += bf2f(rb4.z & 0xffff); v3[1] += bf2f(rb4.z >> 16);
            v3[2] += bf2f(rb4.w & 0xffff); v3[3] += bf2f(rb4.w >> 16);
            float* op = out + (size_t)rowg * 256 + colg;
            *(f32x4*)(op + 0) = v0; *(f32x4*)(op + 4) = v1;
            *(f32x4*)(op + 8) = v2; *(f32x4*)(op + 12) = v3;
        }
    }
}

// ---------- degree count ----------
__global__ void degcnt_k(const int* __restrict__ dst, int* __restrict__ deg, int E)
{
    int e = blockIdx.x * blockDim.x + threadIdx.x;
    if (e < E) atomicAdd(deg + dst[e], 1);
}

// ---------- parallel scan A ----------
__global__ __launch_bounds__(1024) void scanA_k(int* __restrict__ a, int* __restrict__ aux, int n)
{
    __shared__ int wsum[16];
    __shared__ int wpre[16];
    int t = threadIdx.x, lane = t & 63, w = t >> 6;
    int i = blockIdx.x * 1024 + t;
    int v = (i < n) ? a[i] : 0;
    int s = v;
    #pragma unroll
    for (int d = 1; d < 64; d <<= 1) {
        int u = __shfl_up(s, d);
        if (lane >= d) s += u;
    }
    if (lane == 63) wsum[w] = s;
    __syncthreads();
    if (t == 0) {
        int run = 0;
        #pragma unroll
        for (int j = 0; j < 16; ++j) { wpre[j] = run; run += wsum[j]; }
        aux[blockIdx.x] = run;
    }
    __syncthreads();
    if (i < n) a[i] = wpre[w] + s - v;
}

// ---------- scan B ----------
__global__ __launch_bounds__(128) void scanB_k(int* __restrict__ aux, int* __restrict__ tot, int nb)
{
    __shared__ int ws[2];
    int t = threadIdx.x, lane = t & 63, w = t >> 6;
    int v = (t < nb) ? aux[t] : 0;
    int s = v;
    #pragma unroll
    for (int d = 1; d < 64; d <<= 1) {
        int u = __shfl_up(s, d);
        if (lane >= d) s += u;
    }
    if (lane == 63) ws[w] = s;
    __syncthreads();
    int add = (w == 1) ? ws[0] : 0;
    if (t < nb) aux[t] = add + s - v;
    if (t == nb - 1) tot[0] = add + s;
}

// ---------- scan C ----------
__global__ __launch_bounds__(1024) void scanC_k(int* __restrict__ a, const int* __restrict__ aux, int n)
{
    int i = blockIdx.x * 1024 + threadIdx.x;
    if (i < n) a[i] += aux[blockIdx.x];
}

// ---------- CSR scatter ----------
__global__ void scatter_k(
    const int* __restrict__ dst, const int* __restrict__ srcarr,
    const int* __restrict__ off, int* __restrict__ cursor,
    int* __restrict__ csr, int E)
{
    int e = blockIdx.x * blockDim.x + threadIdx.x;
    if (e >= E) return;
    int d = dst[e];
    int pos = off[d] + atomicAdd(cursor + d, 1);
    csr[pos] = srcarr[e];
}

// ---------- fused edge attention v3: parity-split, 8 dims/lane ----------
__global__ __launch_bounds__(256) void attn_k(
    const int* __restrict__ csr, const int* __restrict__ off,
    const unsigned short* __restrict__ Q, const unsigned char* __restrict__ KV8,
    unsigned short* __restrict__ hnew)
{
    int w = threadIdx.x >> 6, lane = threadIdx.x & 63;
    int n = blockIdx.x * 4 + w;
    if (n >= NN) return;
    int e0 = off[n], e1 = off[n + 1];
    int hl = lane & 31, par = lane >> 5;

    const float qs = 0.125f * 1.4426950408889634f;
    f32x2 q01, q23, q45, q67;
    {
        u32x4 qa = __builtin_nontemporal_load((const u32x4*)(Q + (size_t)n * 256 + hl * 8));
        q01[0] = bf2f((unsigned short)(qa.x & 0xffff)) * qs;
        q01[1] = bf2f((unsigned short)(qa.x >> 16)) * qs;
        q23[0] = bf2f((unsigned short)(qa.y & 0xffff)) * qs;
        q23[1] = bf2f((unsigned short)(qa.y >> 16)) * qs;
        q45[0] = bf2f((unsigned short)(qa.z & 0xffff)) * qs;
        q45[1] = bf2f((unsigned short)(qa.z >> 16)) * qs;
        q67[0] = bf2f((unsigned short)(qa.w & 0xffff)) * qs;
        q67[1] = bf2f((unsigned short)(qa.w >> 16)) * qs;
    }
    f32x2 a01 = {0.f, 0.f}, a23 = {0.f, 0.f}, a45 = {0.f, 0.f}, a67 = {0.f, 0.f};
    float s = 0.f;
    const unsigned char* KVl = KV8 + hl * 8;

    int i = e0;
    for (; i + 7 < e1; i += 8) {
        int b[4];
        #pragma unroll
        for (int t2 = 0; t2 < 4; ++t2) b[t2] = csr[i + 2 * t2 + par] << 9;
        u32x2 kd[4], vd[4];
        #pragma unroll
        for (int t2 = 0; t2 < 4; ++t2) {
            kd[t2] = *(const u32x2*)(KVl + (unsigned)b[t2]);
            vd[t2] = *(const u32x2*)(KVl + (unsigned)b[t2] + 256);
        }
        #pragma unroll
        for (int t2 = 0; t2 < 4; ++t2) {
            f32x2 lv = q01 * __builtin_amdgcn_cvt_pk_f32_fp8(kd[t2].x, false);
            lv += q23 * __builtin_amdgcn_cvt_pk_f32_fp8(kd[t2].x, true);
            lv += q45 * __builtin_amdgcn_cvt_pk_f32_fp8(kd[t2].y, false);
            lv += q67 * __builtin_amdgcn_cvt_pk_f32_fp8(kd[t2].y, true);
            float l = lv[0] + lv[1];
            l += __shfl_xor(l, 1);
            l += __shfl_xor(l, 2);
            l += __shfl_xor(l, 4);
            float p = exp2f(l);
            s += p;
            f32x2 pp = {p, p};
            a01 += pp * __builtin_amdgcn_cvt_pk_f32_fp8(vd[t2].x, false);
            a23 += pp * __builtin_amdgcn_cvt_pk_f32_fp8(vd[t2].x, true);
            a45 += pp * __builtin_amdgcn_cvt_pk_f32_fp8(vd[t2].y, false);
            a67 += pp * __builtin_amdgcn_cvt_pk_f32_fp8(vd[t2].y, true);
        }
    }
    for (; i < e1; i += 2) {
        int eidx = i + par;
        int idx = (eidx < e1) ? eidx : (e1 - 1);
        int b = csr[idx] << 9;
        u32x2 kd = *(const u32x2*)(KVl + (unsigned)b);
        u32x2 vd = *(const u32x2*)(KVl + (unsigned)b + 256);
        f32x2 lv = q01 * __builtin_amdgcn_cvt_pk_f32_fp8(kd.x, false);
        lv += q23 * __builtin_amdgcn_cvt_pk_f32_fp8(kd.x, true);
        lv += q45 * __builtin_amdgcn_cvt_pk_f32_fp8(kd.y, false);
        lv += q67 * __builtin_amdgcn_cvt_pk_f32_fp8(kd.y, true);
        float l = lv[0] + lv[1];
        l += __shfl_xor(l, 1);
        l += __shfl_xor(l, 2);
        l += __shfl_xor(l, 4);
        float p = (eidx < e1) ? exp2f(l) : 0.f;
        s += p;
        f32x2 pp = {p, p};
        a01 += pp * __builtin_amdgcn_cvt_pk_f32_fp8(vd.x, false);
        a23 += pp * __builtin_amdgcn_cvt_pk_f32_fp8(vd.x, true);
        a45 += pp * __builtin_amdgcn_cvt_pk_f32_fp8(vd.y, false);
        a67 += pp * __builtin_amdgcn_cvt_pk_f32_fp8(vd.y, true);
    }

    a01[0] += __shfl_xor(a01[0], 32); a01[1] += __shfl_xor(a01[1], 32);
    a23[0] += __shfl_xor(a23[0], 32); a23[1] += __shfl_xor(a23[1], 32);
    a45[0] += __shfl_xor(a45[0], 32); a45[1] += __shfl_xor(a45[1], 32);
    a67[0] += __shfl_xor(a67[0], 32); a67[1] += __shfl_xor(a67[1], 32);
    s += __shfl_xor(s, 32);

    float inv = (e1 > e0) ? 1.0f / s : 0.f;
    if (par == 0) {
        u32x4 ov;
        ov.x = f2bf(a01[0] * inv) | ((unsigned int)f2bf(a01[1] * inv) << 16);
        ov.y = f2bf(a23[0] * inv) | ((unsigned int)f2bf(a23[1] * inv) << 16);
        ov.z = f2bf(a45[0] * inv) | ((unsigned int)f2bf(a45[1] * inv) << 16);
        ov.w = f2bf(a67[0] * inv) | ((unsigned int)f2bf(a67[1] * inv) << 16);
        __builtin_nontemporal_store(ov, (u32x4*)(hnew + (size_t)n * 256 + hl * 8));
    }
}

// ---------- host ----------
extern "C" void kernel_launch(void* const* d_in, const int* in_sizes, int n_in,
                              void* d_out, int out_size, void* d_ws, size_t ws_size,
                              hipStream_t stream)
{
    if (n_in < 19) return;
    const float* h   = (const float*)d_in[0];
    const int*   src = (const int*)d_in[1];
    const int*   dst = (const int*)d_in[2];
    const float* Wq  = (const float*)d_in[3];
    const float* bq  = (const float*)d_in[4];
    const float* Wk  = (const float*)d_in[5];
    const float* bk  = (const float*)d_in[6];
    const float* Wv  = (const float*)d_in[7];
    const float* bv  = (const float*)d_in[8];
    const float* Wo  = (const float*)d_in[9];
    const float* bo  = (const float*)d_in[10];
    const float* W1  = (const float*)d_in[11];
    const float* b1  = (const float*)d_in[12];
    const float* W2  = (const float*)d_in[13];
    const float* b2  = (const float*)d_in[14];
    const float* g1  = (const float*)d_in[15];
    const float* be1 = (const float*)d_in[16];
    const float* g2  = (const float*)d_in[17];
    const float* be2 = (const float*)d_in[18];
    float* out = (float*)d_out;

    char* w = (char*)d_ws;
    unsigned short* hnormb = (unsigned short*)(w + 0);            //  51,200,000 (hnorm -> hnew -> h2)
    unsigned short* Qb     = (unsigned short*)(w + 51200000);     //  51,200,000 (Q -> hmid)
    unsigned char*  KV8    = (unsigned char*)(w + 102400000);     //  51,200,000 (fp8 K|V)
    int*            degoff = (int*)(w + 153600000);               //     400,384 (N+1)
    int*            cursor = (int*)(w + 154000384);               //     400,384
    int*            csr    = (int*)(w + 154400768);               //   6,400,000
    unsigned short* Wqkvt  = (unsigned short*)(w + 204800000);    //     393,216
    unsigned short* Wot    = (unsigned short*)(w + 205193216);    //     131,072
    unsigned short* W1t    = (unsigned short*)(w + 205324288);    //     262,144
    unsigned short* W2t    = (unsigned short*)(w + 205586432);    //     262,144
    float*          bqkv   = (float*)(w + 205848576);             //       3,072
    int*            scanaux= (int*)(w + 205851648);               //         512
    // aliases (temporally disjoint):
    unsigned short* hnewb  = hnormb;
    unsigned short* h2nb   = hnormb;
    unsigned short* hmidb  = Qb;

    hipMemsetAsync(degoff, 0, 400384, stream);
    hipMemsetAsync(cursor, 0, 400384, stream);

    const int M = NN;
    dim3 blk(256);
    dim3 blk512(512);
    const int MB = (M + 127) / 128;             // 782
    const int MB64 = (M + 63) / 64;             // 1563
    const int SCAN_BLKS = (NN + 1023) / 1024;   // 98

    wcv_all_k<<<dim3(513), blk, 0, stream>>>(Wq, Wk, Wv, Wo, W1, W2,
                                             Wqkvt, Wot, W1t, W2t, bq, bk, bv, bqkv);

    degcnt_k<<<dim3((NE + 255) / 256), blk, 0, stream>>>(dst, degoff, NE);
    scanA_k<<<dim3(SCAN_BLKS), dim3(1024), 0, stream>>>(degoff, scanaux, NN);
    scanB_k<<<dim3(1), dim3(128), 0, stream>>>(scanaux, degoff + NN, SCAN_BLKS);
    scanC_k<<<dim3(SCAN_BLKS), dim3(1024), 0, stream>>>(degoff, scanaux, NN);
    scatter_k<<<dim3((NE + 255) / 256), blk, 0, stream>>>(dst, src, degoff, cursor, csr, NE);

    // 1. LN1 -> bf16
    ln_k<<<dim3((NN + 3) / 4), blk, 0, stream>>>(h, g1, be1, hnormb, NN);

    // 2. fused QKV gemm: Q bf16, K/V fp8 (1D grid, XCD-swizzled)
    mgemm_k<3, 2, false, false><<<dim3(3 * MB), blk512, 0, stream>>>(
        hnormb, Wqkvt, bqkv, Qb, KV8, nullptr, nullptr, nullptr, M, 768, 256);

    // 3. fused edge attention -> hnew (bf16)
    attn_k<<<dim3((NN + 3) / 4), blk, 0, stream>>>(csr, degoff, Qb, KV8, hnewb);

    // 4. Wo gemm + residual + fused LN2 -> h2 (bf16) + hmid (bf16)
    dim3 go(1, MB);
    mgemm_k<0, 3, false, true><<<go, blk512, 0, stream>>>(
        hnewb, Wot, bo, h2nb, hmidb, h, g2, be2, M, 256, 256);

    // 5. fused FFN (64-row tiles, 2 wg/CU): out = hmid + relu(h2@W1+b1)@W2 + b2
    mffn_k<<<dim3(1, MB64), blk512, 0, stream>>>(h2nb, W1t, W2t, b1, b2, hmidb, out, M);
}

// Round 20
// 571.363 us; speedup vs baseline: 1.0206x; 1.0206x over previous
//
#include <hip/hip_runtime.h>
#include <hip/hip_bf16.h>

#define NN 100000
#define NE 1600000
// HID=256, HEADS=4, HEAD_DIM=64

typedef __attribute__((ext_vector_type(8))) short bf16x8;
typedef __attribute__((ext_vector_type(4))) float f32x4;
typedef __attribute__((ext_vector_type(2))) float f32x2;
typedef __attribute__((ext_vector_type(2))) unsigned int u32x2;
typedef __attribute__((ext_vector_type(4))) unsigned int u32x4;

// ---------- helpers ----------
__device__ __forceinline__ float bf2f(unsigned short u) {
    union { unsigned int i; float f; } c; c.i = ((unsigned int)u) << 16; return c.f;
}
__device__ __forceinline__ unsigned short f2bf(float f) {
    union { float f; unsigned int i; } c; c.f = f;
    unsigned int lsb = (c.i >> 16) & 1u;
    c.i += 0x7FFFu + lsb;   // round-to-nearest-even
    return (unsigned short)(c.i >> 16);
}
__device__ __forceinline__ u32x4 pack8bf(f32x4 a, f32x4 b) {
    u32x4 p;
    p.x = f2bf(a[0]) | ((unsigned int)f2bf(a[1]) << 16);
    p.y = f2bf(a[2]) | ((unsigned int)f2bf(a[3]) << 16);
    p.z = f2bf(b[0]) | ((unsigned int)f2bf(b[1]) << 16);
    p.w = f2bf(b[2]) | ((unsigned int)f2bf(b[3]) << 16);
    return p;
}
__device__ __forceinline__ unsigned int pack4fp8(f32x4 v) {
    unsigned int w = __builtin_amdgcn_cvt_pk_fp8_f32(v[0], v[1], 0, false);
    return __builtin_amdgcn_cvt_pk_fp8_f32(v[2], v[3], w, true);
}
__device__ __forceinline__ void gload_lds16(const void* g, void* l) {
    __builtin_amdgcn_global_load_lds(
        (const __attribute__((address_space(1))) void*)g,
        (__attribute__((address_space(3))) void*)l, 16, 0, 0);
}

// ---------- LayerNorm (LN1): 4 rows/block, 1 wave/row, bf16 out ----------
__global__ __launch_bounds__(256) void ln_k(
    const float* __restrict__ x, const float* __restrict__ g,
    const float* __restrict__ b, unsigned short* __restrict__ y, int nrows)
{
    int w = threadIdx.x >> 6, lane = threadIdx.x & 63;
    int row = blockIdx.x * 4 + w;
    if (row >= nrows) return;
    const float4 xv = *(const float4*)(x + (size_t)row * 256 + lane * 4);
    float s  = xv.x + xv.y + xv.z + xv.w;
    float sq = xv.x*xv.x + xv.y*xv.y + xv.z*xv.z + xv.w*xv.w;
    #pragma unroll
    for (int m = 1; m < 64; m <<= 1) {
        s  += __shfl_xor(s,  m);
        sq += __shfl_xor(sq, m);
    }
    float mu  = s * (1.0f / 256.0f);
    float var = sq * (1.0f / 256.0f) - mu * mu;
    float r = rsqrtf(var + 1e-5f);
    float4 gv = *(const float4*)(g + lane * 4);
    float4 bv = *(const float4*)(b + lane * 4);
    ushort4 o;
    o.x = f2bf((xv.x - mu) * r * gv.x + bv.x);
    o.y = f2bf((xv.y - mu) * r * gv.y + bv.y);
    o.z = f2bf((xv.z - mu) * r * gv.z + bv.z);
    o.w = f2bf((xv.w - mu) * r * gv.w + bv.w);
    *(ushort4*)(y + (size_t)row * 256 + lane * 4) = o;
}

// ---------- fused weight conversion: all transposes + bias concat in ONE kernel ----------
__global__ __launch_bounds__(256) void wcv_all_k(
    const float* __restrict__ Wq, const float* __restrict__ Wk, const float* __restrict__ Wv,
    const float* __restrict__ Wo, const float* __restrict__ W1, const float* __restrict__ W2,
    unsigned short* __restrict__ Wqkvt, unsigned short* __restrict__ Wot,
    unsigned short* __restrict__ W1t, unsigned short* __restrict__ W2t,
    const float* __restrict__ bq, const float* __restrict__ bk, const float* __restrict__ bv,
    float* __restrict__ bqkv)
{
    int id = blockIdx.x;
    int t = threadIdx.x;
    if (id == 512) {
        bqkv[t] = bq[t]; bqkv[256 + t] = bk[t]; bqkv[512 + t] = bv[t];
        return;
    }
    const float* W; unsigned short* Wt; int K, N, kx, ny;
    if (id < 192) {
        int grp = id >> 6, l = id & 63;
        W = (grp == 0) ? Wq : ((grp == 1) ? Wk : Wv);
        Wt = Wqkvt + grp * 256 * 256;
        K = 256; N = 256; kx = l & 7; ny = l >> 3;
    } else if (id < 256) {
        int l = id - 192; W = Wo; Wt = Wot; K = 256; N = 256; kx = l & 7; ny = l >> 3;
    } else if (id < 384) {
        int l = id - 256; W = W1; Wt = W1t; K = 256; N = 512; kx = l & 7; ny = l >> 3;
    } else {
        int l = id - 384; W = W2; Wt = W2t; K = 512; N = 256; kx = l & 15; ny = l >> 4;
    }
    __shared__ unsigned short tl[32][33];
    int bk2 = kx * 32, bn = ny * 32;
    int lx = t & 31, ly = t >> 5;
    #pragma unroll
    for (int r = 0; r < 32; r += 8)
        tl[ly + r][lx] = f2bf(W[(size_t)(bk2 + ly + r) * N + bn + lx]);
    __syncthreads();
    #pragma unroll
    for (int r = 0; r < 32; r += 8)
        Wt[(size_t)(bn + ly + r) * K + bk2 + lx] = tl[lx][ly + r];
}

// ---------- MFMA bf16 GEMM v5: 3-buffer 2-deep counted-vmcnt pipeline ----------
// 128x256 tile, BK=32, 512 threads = 8 waves (2Mx4N)
// NBX: 0 = 2D launch; >0 = 1D XCD-swizzled (bijective)
// OMODE: 2 QKV split (Q bf16 / KV fp8) | 3 Wo+LN2 fused (outv=h2 bf16, out2=hmid bf16, res=h f32)
template<int NBX, int OMODE, bool RELU, bool RES>
__global__ __launch_bounds__(512) void mgemm_k(
    const unsigned short* __restrict__ A, const unsigned short* __restrict__ Wt,
    const float* __restrict__ bias, void* __restrict__ outv, void* __restrict__ out2,
    const void* __restrict__ res, const float* __restrict__ g, const float* __restrict__ be,
    int M, int N, int K)
{
    __shared__ __align__(16) char lds[73728];
    const int t = threadIdx.x;
    const int lane = t & 63;
    const int wid = t >> 6;
    const int wm = wid >> 2, wn = wid & 3;

    int bmi, bni;
    if (NBX > 0) {
        const int nwg = gridDim.x;
        const int q = nwg >> 3, r = nwg & 7;
        const int xcd = blockIdx.x & 7, idx = blockIdx.x >> 3;
        const int wgid = (xcd < r) ? (xcd * (q + 1) + idx)
                                   : (r * (q + 1) + (xcd - r) * q + idx);
        bmi = wgid / NBX; bni = wgid - bmi * NBX;
    } else {
        bmi = blockIdx.y; bni = blockIdx.x;
    }
    const int bm = bmi * 128, bn = bni * 256;

    f32x4 acc[4][4] = {};

    const int ra_s = t >> 2;
    const int sa_s = (t & 3) ^ (ra_s & 3);
    const size_t arow = (size_t)min(bm + ra_s, M - 1) * K + sa_s * 8;
    const int rb0 = t >> 2;
    const int sb0 = (t & 3) ^ (rb0 & 3);
    const int rb1 = (512 + t) >> 2;
    const int sb1 = (t & 3) ^ (rb1 & 3);
    const size_t brow0 = (size_t)(bn + rb0) * K + sb0 * 8;
    const size_t brow1 = (size_t)(bn + rb1) * K + sb1 * 8;

    const int fr = lane & 15, fs = lane >> 4;
    const int rslot = fs ^ (fr & 3);

    const int KS = K >> 5;

#define STAGE(b, k0) { \
        unsigned short* Ab = (unsigned short*)(lds + (b) * 8192); \
        unsigned short* Bb = (unsigned short*)(lds + 24576 + (b) * 16384); \
        const int kk_ = (k0) << 5; \
        gload_lds16(A + arow + kk_, Ab + t * 8); \
        gload_lds16(Wt + brow0 + kk_, Bb + t * 8); \
        gload_lds16(Wt + brow1 + kk_, Bb + (512 + t) * 8); }

    STAGE(0, 0)
    STAGE(1, 1)
    int cur = 0;
    for (int ks = 0; ks < KS; ++ks) {
        if (ks + 1 < KS) asm volatile("s_waitcnt vmcnt(3)" ::: "memory");
        else             asm volatile("s_waitcnt vmcnt(0)" ::: "memory");
        __builtin_amdgcn_s_barrier();
        if (ks + 2 < KS) {
            int nb = cur + 2; if (nb >= 3) nb -= 3;
            STAGE(nb, ks + 2)
        }
        const unsigned short* As = (const unsigned short*)(lds + cur * 8192);
        const unsigned short* Bs = (const unsigned short*)(lds + 24576 + cur * 16384);
        bf16x8 af[4], bf[4];
        #pragma unroll
        for (int fm = 0; fm < 4; ++fm)
            af[fm] = *(const bf16x8*)&As[(wm * 64 + fm * 16 + fr) * 32 + rslot * 8];
        #pragma unroll
        for (int fn = 0; fn < 4; ++fn)
            bf[fn] = *(const bf16x8*)&Bs[(wn * 64 + fn * 16 + fr) * 32 + rslot * 8];
        #pragma unroll
        for (int fm = 0; fm < 4; ++fm)
            #pragma unroll
            for (int fn = 0; fn < 4; ++fn)
                acc[fm][fn] = __builtin_amdgcn_mfma_f32_16x16x32_bf16(
                    af[fm], bf[fn], acc[fm][fn], 0, 0, 0);
        if (++cur == 3) cur = 0;
    }
#undef STAGE
    __syncthreads();

    // epilogue: per-wave LDS bounce [16 rows][68 stride f32]
    float* wl = (float*)(lds + wid * 4352);
    float* stats = (float*)(lds + 34816);
    const int rr = lane >> 2;
    const int c4 = (lane & 3) * 16;
    const int qg = lane >> 4;

    #pragma unroll
    for (int fm = 0; fm < 4; ++fm) {
        #pragma unroll
        for (int fn = 0; fn < 4; ++fn)
            #pragma unroll
            for (int i = 0; i < 4; ++i)
                wl[(qg * 4 + i) * 68 + fn * 16 + fr] = acc[fm][fn][i];
        f32x4 v0 = *(const f32x4*)&wl[rr * 68 + c4 + 0];
        f32x4 v1 = *(const f32x4*)&wl[rr * 68 + c4 + 4];
        f32x4 v2 = *(const f32x4*)&wl[rr * 68 + c4 + 8];
        f32x4 v3 = *(const f32x4*)&wl[rr * 68 + c4 + 12];
        const int rowg = bm + wm * 64 + fm * 16 + rr;
        const int colg = bn + wn * 64 + c4;
        if (rowg < M) {
            v0 += *(const f32x4*)&bias[colg + 0];
            v1 += *(const f32x4*)&bias[colg + 4];
            v2 += *(const f32x4*)&bias[colg + 8];
            v3 += *(const f32x4*)&bias[colg + 12];
            if (RES) {
                const float* rp = (const float*)res + (size_t)rowg * N + colg;
                v0 += *(const f32x4*)(rp + 0);
                v1 += *(const f32x4*)(rp + 4);
                v2 += *(const f32x4*)(rp + 8);
                v3 += *(const f32x4*)(rp + 12);
            }
            if (RELU) {
                #pragma unroll
                for (int j = 0; j < 4; ++j) {
                    v0[j] = fmaxf(v0[j], 0.f); v1[j] = fmaxf(v1[j], 0.f);
                    v2[j] = fmaxf(v2[j], 0.f); v3[j] = fmaxf(v3[j], 0.f);
                }
            }
        } else {
            v0 = 0.f; v1 = 0.f; v2 = 0.f; v3 = 0.f;
        }

        if (OMODE == 3) {
            acc[fm][0] = v0; acc[fm][1] = v1; acc[fm][2] = v2; acc[fm][3] = v3;
        } else if (rowg < M) {
            // OMODE 2: QKV split
            if (colg < 256) {
                unsigned short* op = (unsigned short*)outv + (size_t)rowg * 256 + colg;
                *(u32x4*)(op + 0) = pack8bf(v0, v1);
                *(u32x4*)(op + 8) = pack8bf(v2, v3);
            } else {
                u32x4 p8;
                p8.x = pack4fp8(v0); p8.y = pack4fp8(v1);
                p8.z = pack4fp8(v2); p8.w = pack4fp8(v3);
                *(u32x4*)((unsigned char*)out2 + (size_t)rowg * 512 + (colg - 256)) = p8;
            }
        }
    }

    if (OMODE == 3) {
        #pragma unroll
        for (int fm = 0; fm < 4; ++fm) {
            float s = 0.f, q = 0.f;
            #pragma unroll
            for (int j = 0; j < 4; ++j)
                #pragma unroll
                for (int c = 0; c < 4; ++c) {
                    float x = acc[fm][j][c];
                    s += x; q += x * x;
                }
            s += __shfl_xor(s, 1); q += __shfl_xor(q, 1);
            s += __shfl_xor(s, 2); q += __shfl_xor(q, 2);
            if ((lane & 3) == 0) {
                int rowl = wm * 64 + fm * 16 + rr;
                stats[rowl * 8 + wn * 2 + 0] = s;
                stats[rowl * 8 + wn * 2 + 1] = q;
            }
        }
        __syncthreads();
        #pragma unroll
        for (int fm = 0; fm < 4; ++fm) {
            const int rowl = wm * 64 + fm * 16 + rr;
            const int rowg = bm + rowl;
            float s = stats[rowl * 8 + 0] + stats[rowl * 8 + 2] + stats[rowl * 8 + 4] + stats[rowl * 8 + 6];
            float q = stats[rowl * 8 + 1] + stats[rowl * 8 + 3] + stats[rowl * 8 + 5] + stats[rowl * 8 + 7];
            float mu = s * (1.0f / 256.0f);
            float var = q * (1.0f / 256.0f) - mu * mu;
            float rstd = rsqrtf(var + 1e-5f);
            const int colg = bn + wn * 64 + c4;
            if (rowg < M) {
                unsigned short* mp = (unsigned short*)out2 + (size_t)rowg * 256 + colg;
                *(u32x4*)(mp + 0) = pack8bf(acc[fm][0], acc[fm][1]);
                *(u32x4*)(mp + 8) = pack8bf(acc[fm][2], acc[fm][3]);
                f32x4 nv[4];
                #pragma unroll
                for (int j = 0; j < 4; ++j) {
                    f32x4 gv = *(const f32x4*)&g[colg + j * 4];
                    f32x4 bv = *(const f32x4*)&be[colg + j * 4];
                    #pragma unroll
                    for (int c = 0; c < 4; ++c)
                        nv[j][c] = (acc[fm][j][c] - mu) * rstd * gv[c] + bv[c];
                }
                unsigned short* op = (unsigned short*)outv + (size_t)rowg * 256 + colg;
                *(u32x4*)(op + 0) = pack8bf(nv[0], nv[1]);
                *(u32x4*)(op + 8) = pack8bf(nv[2], nv[3]);
            }
        }
    }
}

// ---------- fused FFN: out = hmid + relu(h2@W1+b1)@W2 + b2 ----------
// 128 rows/block, 8 waves (2Mx4N). A-tile (h2) LDS-resident; ffnmid half-tiles in LDS.
// LDS: A 64KB @0 | B 2x16KB @65536 | FF 64KB @98304 = 160KB
__global__ __launch_bounds__(512, 2) void mffn_k(
    const unsigned short* __restrict__ A,     // h2 [M][256] bf16
    const unsigned short* __restrict__ W1t,   // [512][256] bf16
    const unsigned short* __restrict__ W2t,   // [256][512] bf16
    const float* __restrict__ b1, const float* __restrict__ b2,
    const unsigned short* __restrict__ hmid,  // [M][256] bf16 residual
    float* __restrict__ out, int M)
{
    __shared__ __align__(16) char lds[163840];
    char* Alds = lds;            // 65536: 8 chunks x 8192 (128 rows x 32k swizzled)
    char* Blds = lds + 65536;    // 32768: 2 x 16384
    char* Flds = lds + 98304;    // 65536: ffnmid half, same chunk format as A

    const int t = threadIdx.x;
    const int lane = t & 63;
    const int wid = t >> 6;
    const int wm = wid >> 2, wn = wid & 3;
    const int bm = blockIdx.y * 128;
    const int fr = lane & 15, fs = lane >> 4;
    const int rslot = fs ^ (fr & 3);

    // ---- stage full A tile (8 chunks of K=32) ----
    const int ra = t >> 2;
    const int sa = (t & 3) ^ (ra & 3);
    const size_t abase = (size_t)min(bm + ra, M - 1) * 256 + sa * 8;
    #pragma unroll
    for (int kc = 0; kc < 8; ++kc)
        gload_lds16(A + abase + kc * 32, Alds + kc * 8192 + t * 16);

    // B staging indices (256 rows x 32k per step, 2 loads/thread)
    const int rb0 = t >> 2;
    const int sb0 = (t & 3) ^ (rb0 & 3);
    const int rb1 = (512 + t) >> 2;
    const int sb1 = (t & 3) ^ (rb1 & 3);

    f32x4 acc2[4][4] = {};

    const int rr = lane >> 2;          // epilogue helpers
    const int qg = lane >> 4;

    for (int nh = 0; nh < 2; ++nh) {
        // ---- FFN1 half: acc1 = A x W1t[nh*256 .. +256][:] ----
        f32x4 acc1[4][4] = {};
        {
            const unsigned short* B1 = W1t + (size_t)(nh * 256) * 256;
            gload_lds16(B1 + (size_t)rb0 * 256 + sb0 * 8, Blds + t * 16);
            gload_lds16(B1 + (size_t)rb1 * 256 + sb1 * 8, Blds + 8192 + t * 16);
            int cur = 0;
            for (int ks = 0; ks < 8; ++ks) {
                __syncthreads();   // drains A (first pass) + B(ks)
                if (ks < 7) {
                    char* bb = Blds + (cur ^ 1) * 16384;
                    gload_lds16(B1 + (size_t)rb0 * 256 + sb0 * 8 + (ks + 1) * 32, bb + t * 16);
                    gload_lds16(B1 + (size_t)rb1 * 256 + sb1 * 8 + (ks + 1) * 32, bb + 8192 + t * 16);
                }
                const unsigned short* As = (const unsigned short*)(Alds + ks * 8192);
                const unsigned short* Bs = (const unsigned short*)(Blds + cur * 16384);
                bf16x8 af[4], bf[4];
                #pragma unroll
                for (int fm = 0; fm < 4; ++fm)
                    af[fm] = *(const bf16x8*)&As[(wm * 64 + fm * 16 + fr) * 32 + rslot * 8];
                #pragma unroll
                for (int fn = 0; fn < 4; ++fn)
                    bf[fn] = *(const bf16x8*)&Bs[(wn * 64 + fn * 16 + fr) * 32 + rslot * 8];
                #pragma unroll
                for (int fm = 0; fm < 4; ++fm)
                    #pragma unroll
                    for (int fn = 0; fn < 4; ++fn)
                        acc1[fm][fn] = __builtin_amdgcn_mfma_f32_16x16x32_bf16(
                            af[fm], bf[fn], acc1[fm][fn], 0, 0, 0);
                cur ^= 1;
            }
        }
        __syncthreads();   // all FFN1 MFMAs done; FF(nh-1) readers done (prev phase barrier)

        // ---- bias + relu -> FF LDS (chunked, swizzled like A staging) ----
        {
            float b1v[4];
            #pragma unroll
            for (int fn = 0; fn < 4; ++fn)
                b1v[fn] = b1[nh * 256 + wn * 64 + fn * 16 + fr];
            #pragma unroll
            for (int fm = 0; fm < 4; ++fm)
                #pragma unroll
                for (int fn = 0; fn < 4; ++fn)
                    #pragma unroll
                    for (int i = 0; i < 4; ++i) {
                        int row = wm * 64 + fm * 16 + qg * 4 + i;     // 0..127
                        int col = wn * 64 + fn * 16 + fr;             // 0..255
                        float v = fmaxf(acc1[fm][fn][i] + b1v[fn], 0.f);
                        int kc = col >> 5;
                        int grp = (col >> 3) & 3;
                        int addr = kc * 8192 + row * 64 + ((grp ^ (row & 3)) * 8 + (col & 7)) * 2;
                        *(unsigned short*)(Flds + addr) = f2bf(v);
                    }
        }
        __syncthreads();   // FF visible to all waves

        // ---- FFN2 half: acc2 += FF x W2t[:, nh*256 .. +256] ----
        {
            const unsigned short* B2 = W2t + nh * 256;
            gload_lds16(B2 + (size_t)rb0 * 512 + sb0 * 8, Blds + t * 16);
            gload_lds16(B2 + (size_t)rb1 * 512 + sb1 * 8, Blds + 8192 + t * 16);
            int cur = 0;
            for (int ks = 0; ks < 8; ++ks) {
                __syncthreads();
                if (ks < 7) {
                    char* bb = Blds + (cur ^ 1) * 16384;
                    gload_lds16(B2 + (size_t)rb0 * 512 + sb0 * 8 + (ks + 1) * 32, bb + t * 16);
                    gload_lds16(B2 + (size_t)rb1 * 512 + sb1 * 8 + (ks + 1) * 32, bb + 8192 + t * 16);
                }
                const unsigned short* Fs = (const unsigned short*)(Flds + ks * 8192);
                const unsigned short* Bs = (const unsigned short*)(Blds + cur * 16384);
                bf16x8 af[4], bf[4];
                #pragma unroll
                for (int fm = 0; fm < 4; ++fm)
                    af[fm] = *(const bf16x8*)&Fs[(wm * 64 + fm * 16 + fr) * 32 + rslot * 8];
                #pragma unroll
                for (int fn = 0; fn < 4; ++fn)
                    bf[fn] = *(const bf16x8*)&Bs[(wn * 64 + fn * 16 + fr) * 32 + rslot * 8];
                #pragma unroll
                for (int fm = 0; fm < 4; ++fm)
                    #pragma unroll
                    for (int fn = 0; fn < 4; ++fn)
                        acc2[fm][fn] = __builtin_amdgcn_mfma_f32_16x16x32_bf16(
                            af[fm], bf[fn], acc2[fm][fn], 0, 0, 0);
                cur ^= 1;
            }
        }
        __syncthreads();   // FFN2 reads done before next nh overwrites FF/B
    }

    // ---- epilogue: + b2 + hmid(bf16) -> out f32 (bounce in A region, now dead) ----
    float* wl = (float*)(Alds + wid * 4352);
    const int c4 = (lane & 3) * 16;
    #pragma unroll
    for (int fm = 0; fm < 4; ++fm) {
        #pragma unroll
        for (int fn = 0; fn < 4; ++fn)
            #pragma unroll
            for (int i = 0; i < 4; ++i)
                wl[(qg * 4 + i) * 68 + fn * 16 + fr] = acc2[fm][fn][i];
        f32x4 v0 = *(const f32x4*)&wl[rr * 68 + c4 + 0];
        f32x4 v1 = *(const f32x4*)&wl[rr * 68 + c4 + 4];
        f32x4 v2 = *(const f32x4*)&wl[rr * 68 + c4 + 8];
        f32x4 v3 = *(const f32x4*)&wl[rr * 68 + c4 + 12];
        const int rowg = bm + wm * 64 + fm * 16 + rr;
        const int colg = wn * 64 + c4;
        if (rowg < M) {
            v0 += *(const f32x4*)&b2[colg + 0];
            v1 += *(const f32x4*)&b2[colg + 4];
            v2 += *(const f32x4*)&b2[colg + 8];
            v3 += *(const f32x4*)&b2[colg + 12];
            const unsigned short* rp = hmid + (size_t)rowg * 256 + colg;
            u32x4 ra4 = *(const u32x4*)rp;
            u32x4 rb4 = *(const u32x4*)(rp + 8);
            v0[0] += bf2f(ra4.x & 0xffff); v0[1] += bf2f(ra4.x >> 16);
            v0[2] += bf2f(ra4.y & 0xffff); v0[3] += bf2f(ra4.y >> 16);
            v1[0] += bf2f(ra4.z & 0xffff); v1[1] += bf2f(ra4.z >> 16);
            v1[2] += bf2f(ra4.w & 0xffff); v1[3] += bf2f(ra4.w >> 16);
            v2[0] += bf2f(rb4.x & 0xffff); v2[1] += bf2f(rb4.x >> 16);
            v2[2] += bf2f(rb4.y & 0xffff); v2[3] += bf2f(rb4.y >> 16);
            v3[0] += bf2f(rb4.z & 0xffff); v3[1] += bf2f(rb4.z >> 16);
            v3[2] += bf2f(rb4.w & 0xffff); v3[3] += bf2f(rb4.w >> 16);
            float* op = out + (size_t)rowg * 256 + colg;
            *(f32x4*)(op + 0) = v0; *(f32x4*)(op + 4) = v1;
            *(f32x4*)(op + 8) = v2; *(f32x4*)(op + 12) = v3;
        }
    }
}

// ---------- degree count ----------
__global__ void degcnt_k(const int* __restrict__ dst, int* __restrict__ deg, int E)
{
    int e = blockIdx.x * blockDim.x + threadIdx.x;
    if (e < E) atomicAdd(deg + dst[e], 1);
}

// ---------- parallel scan A ----------
__global__ __launch_bounds__(1024) void scanA_k(int* __restrict__ a, int* __restrict__ aux, int n)
{
    __shared__ int wsum[16];
    __shared__ int wpre[16];
    int t = threadIdx.x, lane = t & 63, w = t >> 6;
    int i = blockIdx.x * 1024 + t;
    int v = (i < n) ? a[i] : 0;
    int s = v;
    #pragma unroll
    for (int d = 1; d < 64; d <<= 1) {
        int u = __shfl_up(s, d);
        if (lane >= d) s += u;
    }
    if (lane == 63) wsum[w] = s;
    __syncthreads();
    if (t == 0) {
        int run = 0;
        #pragma unroll
        for (int j = 0; j < 16; ++j) { wpre[j] = run; run += wsum[j]; }
        aux[blockIdx.x] = run;
    }
    __syncthreads();
    if (i < n) a[i] = wpre[w] + s - v;
}

// ---------- scan B ----------
__global__ __launch_bounds__(128) void scanB_k(int* __restrict__ aux, int* __restrict__ tot, int nb)
{
    __shared__ int ws[2];
    int t = threadIdx.x, lane = t & 63, w = t >> 6;
    int v = (t < nb) ? aux[t] : 0;
    int s = v;
    #pragma unroll
    for (int d = 1; d < 64; d <<= 1) {
        int u = __shfl_up(s, d);
        if (lane >= d) s += u;
    }
    if (lane == 63) ws[w] = s;
    __syncthreads();
    int add = (w == 1) ? ws[0] : 0;
    if (t < nb) aux[t] = add + s - v;
    if (t == nb - 1) tot[0] = add + s;
}

// ---------- scan C ----------
__global__ __launch_bounds__(1024) void scanC_k(int* __restrict__ a, const int* __restrict__ aux, int n)
{
    int i = blockIdx.x * 1024 + threadIdx.x;
    if (i < n) a[i] += aux[blockIdx.x];
}

// ---------- CSR scatter ----------
__global__ void scatter_k(
    const int* __restrict__ dst, const int* __restrict__ srcarr,
    const int* __restrict__ off, int* __restrict__ cursor,
    int* __restrict__ csr, int E)
{
    int e = blockIdx.x * blockDim.x + threadIdx.x;
    if (e >= E) return;
    int d = dst[e];
    int pos = off[d] + atomicAdd(cursor + d, 1);
    csr[pos] = srcarr[e];
}

// ---------- fused edge attention v3: parity-split, 8 dims/lane ----------
__global__ __launch_bounds__(256) void attn_k(
    const int* __restrict__ csr, const int* __restrict__ off,
    const unsigned short* __restrict__ Q, const unsigned char* __restrict__ KV8,
    unsigned short* __restrict__ hnew)
{
    int w = threadIdx.x >> 6, lane = threadIdx.x & 63;
    int n = blockIdx.x * 4 + w;
    if (n >= NN) return;
    int e0 = off[n], e1 = off[n + 1];
    int hl = lane & 31, par = lane >> 5;

    const float qs = 0.125f * 1.4426950408889634f;
    f32x2 q01, q23, q45, q67;
    {
        u32x4 qa = __builtin_nontemporal_load((const u32x4*)(Q + (size_t)n * 256 + hl * 8));
        q01[0] = bf2f((unsigned short)(qa.x & 0xffff)) * qs;
        q01[1] = bf2f((unsigned short)(qa.x >> 16)) * qs;
        q23[0] = bf2f((unsigned short)(qa.y & 0xffff)) * qs;
        q23[1] = bf2f((unsigned short)(qa.y >> 16)) * qs;
        q45[0] = bf2f((unsigned short)(qa.z & 0xffff)) * qs;
        q45[1] = bf2f((unsigned short)(qa.z >> 16)) * qs;
        q67[0] = bf2f((unsigned short)(qa.w & 0xffff)) * qs;
        q67[1] = bf2f((unsigned short)(qa.w >> 16)) * qs;
    }
    f32x2 a01 = {0.f, 0.f}, a23 = {0.f, 0.f}, a45 = {0.f, 0.f}, a67 = {0.f, 0.f};
    float s = 0.f;
    const unsigned char* KVl = KV8 + hl * 8;

    int i = e0;
    for (; i + 7 < e1; i += 8) {
        int b[4];
        #pragma unroll
        for (int t2 = 0; t2 < 4; ++t2) b[t2] = csr[i + 2 * t2 + par] << 9;
        u32x2 kd[4], vd[4];
        #pragma unroll
        for (int t2 = 0; t2 < 4; ++t2) {
            kd[t2] = *(const u32x2*)(KVl + (unsigned)b[t2]);
            vd[t2] = *(const u32x2*)(KVl + (unsigned)b[t2] + 256);
        }
        #pragma unroll
        for (int t2 = 0; t2 < 4; ++t2) {
            f32x2 lv = q01 * __builtin_amdgcn_cvt_pk_f32_fp8(kd[t2].x, false);
            lv += q23 * __builtin_amdgcn_cvt_pk_f32_fp8(kd[t2].x, true);
            lv += q45 * __builtin_amdgcn_cvt_pk_f32_fp8(kd[t2].y, false);
            lv += q67 * __builtin_amdgcn_cvt_pk_f32_fp8(kd[t2].y, true);
            float l = lv[0] + lv[1];
            l += __shfl_xor(l, 1);
            l += __shfl_xor(l, 2);
            l += __shfl_xor(l, 4);
            float p = exp2f(l);
            s += p;
            f32x2 pp = {p, p};
            a01 += pp * __builtin_amdgcn_cvt_pk_f32_fp8(vd[t2].x, false);
            a23 += pp * __builtin_amdgcn_cvt_pk_f32_fp8(vd[t2].x, true);
            a45 += pp * __builtin_amdgcn_cvt_pk_f32_fp8(vd[t2].y, false);
            a67 += pp * __builtin_amdgcn_cvt_pk_f32_fp8(vd[t2].y, true);
        }
    }
    for (; i < e1; i += 2) {
        int eidx = i + par;
        int idx = (eidx < e1) ? eidx : (e1 - 1);
        int b = csr[idx] << 9;
        u32x2 kd = *(const u32x2*)(KVl + (unsigned)b);
        u32x2 vd = *(const u32x2*)(KVl + (unsigned)b + 256);
        f32x2 lv = q01 * __builtin_amdgcn_cvt_pk_f32_fp8(kd.x, false);
        lv += q23 * __builtin_amdgcn_cvt_pk_f32_fp8(kd.x, true);
        lv += q45 * __builtin_amdgcn_cvt_pk_f32_fp8(kd.y, false);
        lv += q67 * __builtin_amdgcn_cvt_pk_f32_fp8(kd.y, true);
        float l = lv[0] + lv[1];
        l += __shfl_xor(l, 1);
        l += __shfl_xor(l, 2);
        l += __shfl_xor(l, 4);
        float p = (eidx < e1) ? exp2f(l) : 0.f;
        s += p;
        f32x2 pp = {p, p};
        a01 += pp * __builtin_amdgcn_cvt_pk_f32_fp8(vd.x, false);
        a23 += pp * __builtin_amdgcn_cvt_pk_f32_fp8(vd.x, true);
        a45 += pp * __builtin_amdgcn_cvt_pk_f32_fp8(vd.y, false);
        a67 += pp * __builtin_amdgcn_cvt_pk_f32_fp8(vd.y, true);
    }

    a01[0] += __shfl_xor(a01[0], 32); a01[1] += __shfl_xor(a01[1], 32);
    a23[0] += __shfl_xor(a23[0], 32); a23[1] += __shfl_xor(a23[1], 32);
    a45[0] += __shfl_xor(a45[0], 32); a45[1] += __shfl_xor(a45[1], 32);
    a67[0] += __shfl_xor(a67[0], 32); a67[1] += __shfl_xor(a67[1], 32);
    s += __shfl_xor(s, 32);

    float inv = (e1 > e0) ? 1.0f / s : 0.f;
    if (par == 0) {
        u32x4 ov;
        ov.x = f2bf(a01[0] * inv) | ((unsigned int)f2bf(a01[1] * inv) << 16);
        ov.y = f2bf(a23[0] * inv) | ((unsigned int)f2bf(a23[1] * inv) << 16);
        ov.z = f2bf(a45[0] * inv) | ((unsigned int)f2bf(a45[1] * inv) << 16);
        ov.w = f2bf(a67[0] * inv) | ((unsigned int)f2bf(a67[1] * inv) << 16);
        __builtin_nontemporal_store(ov, (u32x4*)(hnew + (size_t)n * 256 + hl * 8));
    }
}

// ---------- host ----------
extern "C" void kernel_launch(void* const* d_in, const int* in_sizes, int n_in,
                              void* d_out, int out_size, void* d_ws, size_t ws_size,
                              hipStream_t stream)
{
    if (n_in < 19) return;
    const float* h   = (const float*)d_in[0];
    const int*   src = (const int*)d_in[1];
    const int*   dst = (const int*)d_in[2];
    const float* Wq  = (const float*)d_in[3];
    const float* bq  = (const float*)d_in[4];
    const float* Wk  = (const float*)d_in[5];
    const float* bk  = (const float*)d_in[6];
    const float* Wv  = (const float*)d_in[7];
    const float* bv  = (const float*)d_in[8];
    const float* Wo  = (const float*)d_in[9];
    const float* bo  = (const float*)d_in[10];
    const float* W1  = (const float*)d_in[11];
    const float* b1  = (const float*)d_in[12];
    const float* W2  = (const float*)d_in[13];
    const float* b2  = (const float*)d_in[14];
    const float* g1  = (const float*)d_in[15];
    const float* be1 = (const float*)d_in[16];
    const float* g2  = (const float*)d_in[17];
    const float* be2 = (const float*)d_in[18];
    float* out = (float*)d_out;

    char* w = (char*)d_ws;
    unsigned short* hnormb = (unsigned short*)(w + 0);            //  51,200,000 (hnorm -> hnew -> h2)
    unsigned short* Qb     = (unsigned short*)(w + 51200000);     //  51,200,000 (Q -> hmid)
    unsigned char*  KV8    = (unsigned char*)(w + 102400000);     //  51,200,000 (fp8 K|V)
    int*            degoff = (int*)(w + 153600000);               //     400,384 (N+1)
    int*            cursor = (int*)(w + 154000384);               //     400,384
    int*            csr    = (int*)(w + 154400768);               //   6,400,000
    unsigned short* Wqkvt  = (unsigned short*)(w + 204800000);    //     393,216
    unsigned short* Wot    = (unsigned short*)(w + 205193216);    //     131,072
    unsigned short* W1t    = (unsigned short*)(w + 205324288);    //     262,144
    unsigned short* W2t    = (unsigned short*)(w + 205586432);    //     262,144
    float*          bqkv   = (float*)(w + 205848576);             //       3,072
    int*            scanaux= (int*)(w + 205851648);               //         512
    // aliases (temporally disjoint):
    unsigned short* hnewb  = hnormb;
    unsigned short* h2nb   = hnormb;
    unsigned short* hmidb  = Qb;

    hipMemsetAsync(degoff, 0, 400384, stream);
    hipMemsetAsync(cursor, 0, 400384, stream);

    const int M = NN;
    dim3 blk(256);
    dim3 blk512(512);
    const int MB = (M + 127) / 128;             // 782
    const int SCAN_BLKS = (NN + 1023) / 1024;   // 98

    wcv_all_k<<<dim3(513), blk, 0, stream>>>(Wq, Wk, Wv, Wo, W1, W2,
                                             Wqkvt, Wot, W1t, W2t, bq, bk, bv, bqkv);

    degcnt_k<<<dim3((NE + 255) / 256), blk, 0, stream>>>(dst, degoff, NE);
    scanA_k<<<dim3(SCAN_BLKS), dim3(1024), 0, stream>>>(degoff, scanaux, NN);
    scanB_k<<<dim3(1), dim3(128), 0, stream>>>(scanaux, degoff + NN, SCAN_BLKS);
    scanC_k<<<dim3(SCAN_BLKS), dim3(1024), 0, stream>>>(degoff, scanaux, NN);
    scatter_k<<<dim3((NE + 255) / 256), blk, 0, stream>>>(dst, src, degoff, cursor, csr, NE);

    // 1. LN1 -> bf16
    ln_k<<<dim3((NN + 3) / 4), blk, 0, stream>>>(h, g1, be1, hnormb, NN);

    // 2. fused QKV gemm: Q bf16, K/V fp8 (1D grid, XCD-swizzled)
    mgemm_k<3, 2, false, false><<<dim3(3 * MB), blk512, 0, stream>>>(
        hnormb, Wqkvt, bqkv, Qb, KV8, nullptr, nullptr, nullptr, M, 768, 256);

    // 3. fused edge attention -> hnew (bf16)
    attn_k<<<dim3((NN + 3) / 4), blk, 0, stream>>>(csr, degoff, Qb, KV8, hnewb);

    // 4. Wo gemm + residual + fused LN2 -> h2 (bf16) + hmid (bf16)
    dim3 go(1, MB);
    mgemm_k<0, 3, false, true><<<go, blk512, 0, stream>>>(
        hnewb, Wot, bo, h2nb, hmidb, h, g2, be2, M, 256, 256);

    // 5. fused FFN: out = hmid + relu(h2@W1+b1)@W2 + b2
    mffn_k<<<go, blk512, 0, stream>>>(h2nb, W1t, W2t, b1, b2, hmidb, out, M);
}